// Round 7
// baseline (5139.568 us; speedup 1.0000x reference)
//
#include <hip/hip_runtime.h>
#include <hip/hip_bf16.h>

#define BB 4
#define SS 512
#define HH 768
#define VV 35000
#define JJ 45
#define NGATE 5
#define NN (BB*JJ)     // 180
#define H3 (3*HH)      // 2304
#define BS 256

// ---- static device scratch: independent of ws_size ----
__device__ float g_wA[NN*HH];
__device__ float g_wB[NN*HH];
__device__ float g_hA[NN*HH];
__device__ float g_hB[NN*HH];
__device__ float g_gi[NN*H3];
__device__ float g_gh[NN*H3];
__device__ float g_ahist[NN*SS];
__device__ float g_ctx[NN*HH];
__device__ float g_pgen[NN];
__device__ float g_pfin[(size_t)NN*VV];   // 25.2 MB logits

__device__ __forceinline__ float* bufSel(int sel) {
    switch (sel) {
        case 0: return g_wA; case 1: return g_wB;
        case 2: return g_hA; case 3: return g_hB;
        case 4: return g_gi; case 5: return g_gh;
        default: return g_pfin;
    }
}
__device__ __forceinline__ float* wcurOf(int t) { return (t & 1) ? g_wB : g_wA; }
__device__ __forceinline__ float* wnxtOf(int t) { return (t & 1) ? g_wA : g_wB; }
__device__ __forceinline__ float* hcurOf(int t) { return (t & 1) ? g_hB : g_hA; }
__device__ __forceinline__ float* hnewOf(int t) { return (t & 1) ? g_hA : g_hB; }

// ---- LDS-tree block reductions (uniform calls only) ----
__device__ __forceinline__ float bsum(float v, float* sc) {
    int t = threadIdx.x;
    sc[t] = v; __syncthreads();
    #pragma unroll
    for (int off = BS/2; off > 0; off >>= 1) {
        if (t < off) sc[t] += sc[t + off];
        __syncthreads();
    }
    float r = sc[0]; __syncthreads();
    return r;
}
__device__ __forceinline__ float bmax(float v, float* sc) {
    int t = threadIdx.x;
    sc[t] = v; __syncthreads();
    #pragma unroll
    for (int off = BS/2; off > 0; off >>= 1) {
        if (t < off) sc[t] = fmaxf(sc[t], sc[t + off]);
        __syncthreads();
    }
    float r = sc[0]; __syncthreads();
    return r;
}
__device__ __forceinline__ float wsum64(float v, volatile float* w, int lane) {
    w[lane] = v;
    #pragma unroll
    for (int off = 32; off > 0; off >>= 1) {
        if (lane < off) w[lane] = w[lane] + w[lane + off];
    }
    return w[0];
}

// ---- init ----
__global__ __launch_bounds__(256) void init_wh(
    const int* __restrict__ slot, const float* __restrict__ embed,
    const float* __restrict__ hidden, int lslot)
{
    int n = blockIdx.x, b = n / JJ, j = n % JJ;
    for (int h = threadIdx.x; h < HH; h += 256) {
        float v = 0.f;
        for (int l = 0; l < lslot; l++) {
            int s = slot[j*lslot + l];
            if (s < 0) s = 0; if (s >= VV) s = VV - 1;
            v += embed[(size_t)s*HH + h];
        }
        g_wA[(size_t)n*HH + h] = v;
        g_hA[(size_t)n*HH + h] = hidden[(size_t)b*HH + h];
    }
}

// ---- C(RxM) = A(RxK) * B(MxK)^T (+bias) ; 64x64x16 tiles ----
__global__ __launch_bounds__(256) void gemm_abt(
    int aSel, const float* __restrict__ Bw,
    const float* __restrict__ bias, int cSel,
    int R, int K, int M, int ldc)
{
    const float* A = bufSel(aSel);
    float*       C = bufSel(cSel);
    __shared__ float As[16][68];
    __shared__ float Bs[16][68];
    const int tid  = threadIdx.x;
    const int r0   = blockIdx.y * 64;
    const int m0   = blockIdx.x * 64;
    const int lrow = tid >> 2;
    const int lkg  = (tid & 3) * 4;
    const int tx   = tid & 15, ty = tid >> 4;
    float acc[4][4] = {};

    for (int k0 = 0; k0 < K; k0 += 16) {
        float4 av = make_float4(0.f, 0.f, 0.f, 0.f);
        int ar = r0 + lrow;
        if (ar < R) av = *(const float4*)(A + (size_t)ar*K + k0 + lkg);
        As[lkg+0][lrow] = av.x; As[lkg+1][lrow] = av.y;
        As[lkg+2][lrow] = av.z; As[lkg+3][lrow] = av.w;

        float4 bv = make_float4(0.f, 0.f, 0.f, 0.f);
        int br = m0 + lrow;
        if (br < M) bv = *(const float4*)(Bw + (size_t)br*K + k0 + lkg);
        Bs[lkg+0][lrow] = bv.x; Bs[lkg+1][lrow] = bv.y;
        Bs[lkg+2][lrow] = bv.z; Bs[lkg+3][lrow] = bv.w;
        __syncthreads();

        #pragma unroll
        for (int kk = 0; kk < 16; kk++) {
            float4 a = *(const float4*)&As[kk][ty*4];
            float4 b = *(const float4*)&Bs[kk][tx*4];
            acc[0][0] += a.x*b.x; acc[0][1] += a.x*b.y; acc[0][2] += a.x*b.z; acc[0][3] += a.x*b.w;
            acc[1][0] += a.y*b.x; acc[1][1] += a.y*b.y; acc[1][2] += a.y*b.z; acc[1][3] += a.y*b.w;
            acc[2][0] += a.z*b.x; acc[2][1] += a.z*b.y; acc[2][2] += a.z*b.z; acc[2][3] += a.z*b.w;
            acc[3][0] += a.w*b.x; acc[3][1] += a.w*b.y; acc[3][2] += a.w*b.z; acc[3][3] += a.w*b.w;
        }
        __syncthreads();
    }

    #pragma unroll
    for (int i = 0; i < 4; i++) {
        int r = r0 + ty*4 + i;
        if (r >= R) continue;
        #pragma unroll
        for (int j = 0; j < 4; j++) {
            int m = m0 + tx*4 + j;
            if (m < M) {
                float v = acc[i][j];
                if (bias) v += bias[m];
                C[(size_t)r*ldc + m] = v;
            }
        }
    }
}

// ---- GRU gate combine ----
__global__ __launch_bounds__(256) void gru_combine(int t)
{
    int idx = blockIdx.x * 256 + threadIdx.x;
    if (idx >= NN*HH) return;
    int n = idx / HH, k = idx % HH;
    const float* gin = g_gi + (size_t)n*H3;
    const float* ghn = g_gh + (size_t)n*H3;
    float r  = 1.f / (1.f + expf(-(gin[k]        + ghn[k])));
    float z  = 1.f / (1.f + expf(-(gin[HH+k]     + ghn[HH+k])));
    float nn = tanhf(gin[2*HH+k] + r * ghn[2*HH+k]);
    hnewOf(t)[idx] = (1.f - z) * nn + z * hcurOf(t)[idx];
}

// ---- attention + context + p_gen (one block per n) ----
__global__ __launch_bounds__(256) void attn_kernel(
    int t, const float* __restrict__ enc, const int* __restrict__ masks,
    const float* __restrict__ wgenW, const float* __restrict__ wgenb)
{
    int n = blockIdx.x, b = n / JJ;
    int tid = threadIdx.x, lane = tid & 63, wid = tid >> 6;
    const float* hnew = hnewOf(t);
    const float* wcur = wcurOf(t);
    __shared__ float hsh[HH], esh[SS], csh[HH], sc[BS];
    __shared__ float wred[4][64];

    for (int i = tid; i < HH; i += 256) hsh[i] = hnew[(size_t)n*HH + i];
    __syncthreads();

    for (int s = wid; s < SS; s += 4) {
        const float* ep = enc + ((size_t)b*SS + s)*HH;
        float acc = 0.f;
        for (int i = lane; i < HH; i += 64) acc += ep[i] * hsh[i];
        float tot = wsum64(acc, wred[wid], lane);
        if (lane == 0) esh[s] = (masks[b*SS + s] != 1) ? -1e9f : tot;
    }
    __syncthreads();

    float Mx  = bmax(fmaxf(esh[tid], esh[tid + 256]), sc);
    float e1  = expf(esh[tid] - Mx), e2 = expf(esh[tid + 256] - Mx);
    float Sm  = bsum(e1 + e2, sc);
    float inv = 1.f / Sm;
    esh[tid] = e1 * inv; esh[tid + 256] = e2 * inv;
    g_ahist[(size_t)n*SS + tid]       = esh[tid];
    g_ahist[(size_t)n*SS + tid + 256] = esh[tid + 256];
    __syncthreads();

    for (int h = tid; h < HH; h += 256) {
        const float* ep = enc + (size_t)b*SS*HH + h;
        float acc = 0.f;
        for (int s = 0; s < SS; s++) acc += esh[s] * ep[(size_t)s*HH];
        csh[h] = acc;
        g_ctx[(size_t)n*HH + h] = acc;
    }
    __syncthreads();

    float p = 0.f;
    for (int i = tid; i < HH; i += 256)
        p += wcur[(size_t)n*HH + i] * wgenW[i]
           + hsh[i]                 * wgenW[HH + i]
           + csh[i]                 * wgenW[2*HH + i];
    p = bsum(p, sc);
    if (tid == 0)
        g_pgen[n] = 1.f / (1.f + expf(-(p + wgenb[0])));
}

// ---- FUSED: softmax + scatter + f32-out + argmax + w_next (one block per n)
// Per-thread stripe ownership (v == tid mod 256): every row element is
// normalized, scattered-into, re-read and emitted by the SAME thread.
__global__ __launch_bounds__(256) void vocab_out_kernel(
    const int* __restrict__ ids, const float* __restrict__ embed,
    float* __restrict__ outp, int t, int T)
{
    int n = blockIdx.x, b = n / JJ;
    int tid = threadIdx.x;
    float* row = g_pfin + (size_t)n*VV;
    __shared__ float sc[BS];
    __shared__ float sv[BS]; __shared__ int si[BS];
    __shared__ int sWidx;

    float m = -1e30f;
    for (int v = tid; v < VV; v += 256) m = fmaxf(m, row[v]);
    float Mx = bmax(m, sc);

    float s = 0.f;
    for (int v = tid; v < VV; v += 256) s += expf(row[v] - Mx);
    float Sm = bsum(s, sc);

    float pg = g_pgen[n];
    float scale = pg / Sm;
    float c = 1.f - pg;

    for (int v = tid; v < VV; v += 256) row[v] = expf(row[v] - Mx) * scale;
    for (int q = 0; q < SS; q++) {
        int id = ids[b*SS + q];
        id = (id < 0) ? 0 : (id >= VV ? VV - 1 : id);
        if ((id & 255) == tid) row[id] += c * g_ahist[(size_t)n*SS + q];
    }

    float* orow = outp + ((size_t)n*T + t)*VV;
    float bv = -1e30f; int bi = VV - 1;
    for (int v = tid; v < VV; v += 256) {
        float x = row[v];
        orow[v] = x;
        if (x > bv) { bv = x; bi = v; }   // strict >: first max within stripe
    }
    sv[tid] = bv; si[tid] = bi; __syncthreads();
    #pragma unroll
    for (int off = BS/2; off > 0; off >>= 1) {
        if (tid < off) {
            if (sv[tid+off] > sv[tid] ||
                (sv[tid+off] == sv[tid] && si[tid+off] < si[tid])) {
                sv[tid] = sv[tid+off]; si[tid] = si[tid+off];
            }
        }
        __syncthreads();
    }
    if (tid == 0) {
        int fi = si[0];
        if (fi < 0) fi = 0; if (fi >= VV) fi = VV - 1;
        sWidx = fi;
    }
    __syncthreads();
    int widx = sWidx;
    float* wnext = wnxtOf(t);
    for (int h = tid; h < HH; h += 256)
        wnext[(size_t)n*HH + h] = embed[(size_t)widx*HH + h];
}

// ---- gate (t==0 only) ----
__global__ __launch_bounds__(256) void gate_kernel(
    const float* __restrict__ WgW, const float* __restrict__ Wgb,
    float* __restrict__ outg)
{
    int n = blockIdx.x;
    int tid = threadIdx.x;
    __shared__ float sc[BS];
    for (int g = 0; g < NGATE; g++) {
        float p = 0.f;
        for (int i = tid; i < HH; i += 256)
            p += g_ctx[(size_t)n*HH + i] * WgW[(size_t)g*HH + i];
        p = bsum(p, sc);
        if (tid == 0)
            outg[n*NGATE + g] = p + Wgb[g];
        __syncthreads();
    }
}

extern "C" void kernel_launch(void* const* d_in, const int* in_sizes, int n_in,
                              void* d_out, int out_size, void* d_ws, size_t ws_size,
                              hipStream_t stream)
{
    const int*   input_ids = (const int*)d_in[0];
    const float* enc       = (const float*)d_in[1];
    const float* hidden    = (const float*)d_in[2];
    const int*   masks     = (const int*)d_in[3];
    const int*   slot      = (const int*)d_in[4];
    // d_in[5] = max_len (device scalar) — T derived from out_size
    const float* embed     = (const float*)d_in[6];
    const float* Wih       = (const float*)d_in[7];
    const float* Whh       = (const float*)d_in[8];
    const float* bih       = (const float*)d_in[9];
    const float* bhh       = (const float*)d_in[10];
    const float* wgenW     = (const float*)d_in[11];
    const float* wgenb     = (const float*)d_in[12];
    const float* wgateW    = (const float*)d_in[13];
    const float* wgateb    = (const float*)d_in[14];
    float* out = (float*)d_out;     // OUTPUT IS FLOAT32 (fingerprint-proven R6)
    const int lslot = in_sizes[4] / JJ;
    int T = (int)(((long long)out_size - (long long)NN*NGATE) / ((long long)NN*VV));
    if (T < 1) T = 1; if (T > 16) T = 16;
    (void)d_ws; (void)ws_size; (void)n_in;

    init_wh<<<NN, 256, 0, stream>>>(slot, embed, hidden, lslot);

    for (int t = 0; t < T; t++) {
        int wSel = (t & 1) ? 1 : 0;   // wcur
        int hSel = (t & 1) ? 3 : 2;   // hcur
        int nSel = (t & 1) ? 2 : 3;   // hnew

        gemm_abt<<<dim3(H3/64, 3), 256, 0, stream>>>(wSel, Wih, bih, 4, NN, HH, H3, H3);
        gemm_abt<<<dim3(H3/64, 3), 256, 0, stream>>>(hSel, Whh, bhh, 5, NN, HH, H3, H3);
        gru_combine<<<(NN*HH + 255)/256, 256, 0, stream>>>(t);
        attn_kernel<<<NN, 256, 0, stream>>>(t, enc, masks, wgenW, wgenb);
        gemm_abt<<<dim3((VV + 63)/64, 3), 256, 0, stream>>>(nSel, embed, nullptr, 6,
                                                            NN, HH, VV, VV);
        vocab_out_kernel<<<NN, 256, 0, stream>>>(input_ids, embed, out, t, T);
        if (t == 0)
            gate_kernel<<<NN, 256, 0, stream>>>(wgateW, wgateb,
                                                out + (size_t)NN*T*VV);
    }
}

// Round 8
// 2800.399 us; speedup vs baseline: 1.8353x; 1.8353x over previous
//
#include <hip/hip_runtime.h>
#include <hip/hip_bf16.h>

#define BB 4
#define SS 512
#define HH 768
#define VV 35000
#define JJ 45
#define NGATE 5
#define NN (BB*JJ)     // 180
#define H3 (3*HH)      // 2304
#define BS 256

// ---- static device scratch: independent of ws_size ----
__device__ float g_wA[NN*HH];
__device__ float g_wB[NN*HH];
__device__ float g_hA[NN*HH];
__device__ float g_hB[NN*HH];
__device__ float g_gi[NN*H3];
__device__ float g_gh[NN*H3];
__device__ float g_esc[NN*SS];            // raw attention scores
__device__ float g_ahist[NN*SS];
__device__ float g_ctx[NN*HH];
__device__ float g_pgen[NN];
__device__ float g_pfin[(size_t)NN*VV];   // 25.2 MB logits

__device__ __forceinline__ float* bufSel(int sel) {
    switch (sel) {
        case 0: return g_wA; case 1: return g_wB;
        case 2: return g_hA; case 3: return g_hB;
        case 4: return g_gi; case 5: return g_gh;
        default: return g_pfin;
    }
}
__device__ __forceinline__ float* wcurOf(int t) { return (t & 1) ? g_wB : g_wA; }
__device__ __forceinline__ float* wnxtOf(int t) { return (t & 1) ? g_wA : g_wB; }
__device__ __forceinline__ float* hcurOf(int t) { return (t & 1) ? g_hB : g_hA; }
__device__ __forceinline__ float* hnewOf(int t) { return (t & 1) ? g_hA : g_hB; }

// ---- LDS-tree block reductions (once per block — not in hot loops) ----
__device__ __forceinline__ float bsum(float v, float* sc) {
    int t = threadIdx.x;
    sc[t] = v; __syncthreads();
    #pragma unroll
    for (int off = BS/2; off > 0; off >>= 1) {
        if (t < off) sc[t] += sc[t + off];
        __syncthreads();
    }
    float r = sc[0]; __syncthreads();
    return r;
}
__device__ __forceinline__ float bmax(float v, float* sc) {
    int t = threadIdx.x;
    sc[t] = v; __syncthreads();
    #pragma unroll
    for (int off = BS/2; off > 0; off >>= 1) {
        if (t < off) sc[t] = fmaxf(sc[t], sc[t + off]);
        __syncthreads();
    }
    float r = sc[0]; __syncthreads();
    return r;
}

// ---- init ----
__global__ __launch_bounds__(256) void init_wh(
    const int* __restrict__ slot, const float* __restrict__ embed,
    const float* __restrict__ hidden, int lslot)
{
    int n = blockIdx.x, b = n / JJ, j = n % JJ;
    for (int h = threadIdx.x; h < HH; h += 256) {
        float v = 0.f;
        for (int l = 0; l < lslot; l++) {
            int s = slot[j*lslot + l];
            if (s < 0) s = 0; if (s >= VV) s = VV - 1;
            v += embed[(size_t)s*HH + h];
        }
        g_wA[(size_t)n*HH + h] = v;
        g_hA[(size_t)n*HH + h] = hidden[(size_t)b*HH + h];
    }
}

// ---- shared 64x64x16 A*B^T tile body ----
// C[r,m] = sum_k A[r,k]*B[m,k]  (A: RxK lda=K, B: MxK ldb=K)
__device__ __forceinline__ void gemm_tile_abt(
    const float* A, const float* B, const float* bias, float* C,
    int R, int K, int M, int ldc, int r0, int m0)
{
    __shared__ float As[16][68];
    __shared__ float Bs[16][68];
    const int tid  = threadIdx.x;
    const int lrow = tid >> 2;
    const int lkg  = (tid & 3) * 4;
    const int tx   = tid & 15, ty = tid >> 4;
    float acc[4][4] = {};

    for (int k0 = 0; k0 < K; k0 += 16) {
        float4 av = make_float4(0.f, 0.f, 0.f, 0.f);
        int ar = r0 + lrow;
        if (ar < R) av = *(const float4*)(A + (size_t)ar*K + k0 + lkg);
        As[lkg+0][lrow] = av.x; As[lkg+1][lrow] = av.y;
        As[lkg+2][lrow] = av.z; As[lkg+3][lrow] = av.w;

        float4 bv = make_float4(0.f, 0.f, 0.f, 0.f);
        int br = m0 + lrow;
        if (br < M) bv = *(const float4*)(B + (size_t)br*K + k0 + lkg);
        Bs[lkg+0][lrow] = bv.x; Bs[lkg+1][lrow] = bv.y;
        Bs[lkg+2][lrow] = bv.z; Bs[lkg+3][lrow] = bv.w;
        __syncthreads();

        #pragma unroll
        for (int kk = 0; kk < 16; kk++) {
            float4 a = *(const float4*)&As[kk][ty*4];
            float4 b = *(const float4*)&Bs[kk][tx*4];
            acc[0][0] += a.x*b.x; acc[0][1] += a.x*b.y; acc[0][2] += a.x*b.z; acc[0][3] += a.x*b.w;
            acc[1][0] += a.y*b.x; acc[1][1] += a.y*b.y; acc[1][2] += a.y*b.z; acc[1][3] += a.y*b.w;
            acc[2][0] += a.z*b.x; acc[2][1] += a.z*b.y; acc[2][2] += a.z*b.z; acc[2][3] += a.z*b.w;
            acc[3][0] += a.w*b.x; acc[3][1] += a.w*b.y; acc[3][2] += a.w*b.z; acc[3][3] += a.w*b.w;
        }
        __syncthreads();
    }

    #pragma unroll
    for (int i = 0; i < 4; i++) {
        int r = r0 + ty*4 + i;
        if (r >= R) continue;
        #pragma unroll
        for (int j = 0; j < 4; j++) {
            int m = m0 + tx*4 + j;
            if (m < M) {
                float v = acc[i][j];
                if (bias) v += bias[m];
                C[(size_t)r*ldc + m] = v;
            }
        }
    }
}

// ---- generic GEMM (scratch A -> scratch C), grid (M/64, R/64) ----
__global__ __launch_bounds__(256) void gemm_abt(
    int aSel, const float* __restrict__ Bw, const float* __restrict__ bias,
    int cSel, int R, int K, int M, int ldc)
{
    gemm_tile_abt(bufSel(aSel), Bw, bias, bufSel(cSel),
                  R, K, M, ldc, blockIdx.y * 64, blockIdx.x * 64);
}

// ---- attention scores: per b, E[45xSS] = Hnew_b[45xHH] @ enc_b[SSxHH]^T ----
__global__ __launch_bounds__(256) void score_gemm(int t, const float* __restrict__ enc)
{
    int b = blockIdx.z;
    const float* A = hnewOf(t) + (size_t)b*JJ*HH;
    const float* B = enc       + (size_t)b*SS*HH;
    float*       C = g_esc     + (size_t)b*JJ*SS;
    gemm_tile_abt(A, B, nullptr, C, JJ, HH, SS, SS, 0, blockIdx.x * 64);
}

// ---- softmax over s (mask) -> ahist ; one block per n ----
__global__ __launch_bounds__(256) void attn_soft(const int* __restrict__ masks)
{
    int n = blockIdx.x, b = n / JJ;
    int tid = threadIdx.x;
    __shared__ float sc[BS];
    const float* E = g_esc + (size_t)n*SS;
    float e1 = (masks[b*SS + tid]       != 1) ? -1e9f : E[tid];
    float e2 = (masks[b*SS + tid + 256] != 1) ? -1e9f : E[tid + 256];
    float Mx = bmax(fmaxf(e1, e2), sc);
    float x1 = expf(e1 - Mx), x2 = expf(e2 - Mx);
    float Sm = bsum(x1 + x2, sc);
    float inv = 1.f / Sm;
    g_ahist[(size_t)n*SS + tid]       = x1 * inv;
    g_ahist[(size_t)n*SS + tid + 256] = x2 * inv;
}

// ---- context: per b, C[45xHH] = ahist_b[45xSS] @ enc_b[SSxHH] (A*B) ----
__global__ __launch_bounds__(256) void ctx_gemm(const float* __restrict__ enc)
{
    int b = blockIdx.z;
    const float* A = g_ahist + (size_t)b*JJ*SS;   // 45 x 512
    const float* B = enc     + (size_t)b*SS*HH;   // 512 x 768
    float*       C = g_ctx   + (size_t)b*JJ*HH;   // 45 x 768
    const int m0 = blockIdx.x * 64;               // h-tile

    __shared__ float As[16][68];
    __shared__ float Bs[16][68];
    const int tid  = threadIdx.x;
    const int lrow = tid >> 2;          // 0..63 (A: j rows)
    const int lkg  = (tid & 3) * 4;     // A k-group
    const int bkr  = tid >> 4;          // 0..15 (B: k rows)
    const int bmc  = (tid & 15) * 4;    // B m-cols
    const int tx   = tid & 15, ty = tid >> 4;
    float acc[4][4] = {};

    for (int k0 = 0; k0 < SS; k0 += 16) {
        float4 av = make_float4(0.f, 0.f, 0.f, 0.f);
        if (lrow < JJ) av = *(const float4*)(A + (size_t)lrow*SS + k0 + lkg);
        As[lkg+0][lrow] = av.x; As[lkg+1][lrow] = av.y;
        As[lkg+2][lrow] = av.z; As[lkg+3][lrow] = av.w;

        float4 bv = *(const float4*)(B + (size_t)(k0 + bkr)*HH + m0 + bmc);
        Bs[bkr][bmc+0] = bv.x; Bs[bkr][bmc+1] = bv.y;
        Bs[bkr][bmc+2] = bv.z; Bs[bkr][bmc+3] = bv.w;
        __syncthreads();

        #pragma unroll
        for (int kk = 0; kk < 16; kk++) {
            float4 a = *(const float4*)&As[kk][ty*4];
            float4 b2 = *(const float4*)&Bs[kk][tx*4];
            acc[0][0] += a.x*b2.x; acc[0][1] += a.x*b2.y; acc[0][2] += a.x*b2.z; acc[0][3] += a.x*b2.w;
            acc[1][0] += a.y*b2.x; acc[1][1] += a.y*b2.y; acc[1][2] += a.y*b2.z; acc[1][3] += a.y*b2.w;
            acc[2][0] += a.z*b2.x; acc[2][1] += a.z*b2.y; acc[2][2] += a.z*b2.z; acc[2][3] += a.z*b2.w;
            acc[3][0] += a.w*b2.x; acc[3][1] += a.w*b2.y; acc[3][2] += a.w*b2.z; acc[3][3] += a.w*b2.w;
        }
        __syncthreads();
    }

    #pragma unroll
    for (int i = 0; i < 4; i++) {
        int j = ty*4 + i;
        if (j >= JJ) continue;
        #pragma unroll
        for (int q = 0; q < 4; q++)
            C[(size_t)j*HH + m0 + tx*4 + q] = acc[i][q];
    }
}

// ---- p_gen: one block per n ----
__global__ __launch_bounds__(256) void pgen_kernel(
    int t, const float* __restrict__ wgenW, const float* __restrict__ wgenb)
{
    int n = blockIdx.x;
    int tid = threadIdx.x;
    __shared__ float sc[BS];
    const float* wcur = wcurOf(t);
    const float* hnew = hnewOf(t);
    float p = 0.f;
    for (int i = tid; i < HH; i += 256)
        p += wcur[(size_t)n*HH + i] * wgenW[i]
           + hnew[(size_t)n*HH + i] * wgenW[HH + i]
           + g_ctx[(size_t)n*HH + i] * wgenW[2*HH + i];
    p = bsum(p, sc);
    if (tid == 0)
        g_pgen[n] = 1.f / (1.f + expf(-(p + wgenb[0])));
}

// ---- GRU gate combine ----
__global__ __launch_bounds__(256) void gru_combine(int t)
{
    int idx = blockIdx.x * 256 + threadIdx.x;
    if (idx >= NN*HH) return;
    int n = idx / HH, k = idx % HH;
    const float* gin = g_gi + (size_t)n*H3;
    const float* ghn = g_gh + (size_t)n*H3;
    float r  = 1.f / (1.f + expf(-(gin[k]        + ghn[k])));
    float z  = 1.f / (1.f + expf(-(gin[HH+k]     + ghn[HH+k])));
    float nn = tanhf(gin[2*HH+k] + r * ghn[2*HH+k]);
    hnewOf(t)[idx] = (1.f - z) * nn + z * hcurOf(t)[idx];
}

// ---- FUSED: vocab softmax + scatter + f32-out + argmax + w_next ----
__global__ __launch_bounds__(256) void vocab_out_kernel(
    const int* __restrict__ ids, const float* __restrict__ embed,
    float* __restrict__ outp, int t, int T)
{
    int n = blockIdx.x, b = n / JJ;
    int tid = threadIdx.x;
    float* row = g_pfin + (size_t)n*VV;
    __shared__ float sc[BS];
    __shared__ float sv[BS]; __shared__ int si[BS];
    __shared__ int sWidx;

    float m = -1e30f;
    for (int v = tid; v < VV; v += 256) m = fmaxf(m, row[v]);
    float Mx = bmax(m, sc);

    float s = 0.f;
    for (int v = tid; v < VV; v += 256) s += expf(row[v] - Mx);
    float Sm = bsum(s, sc);

    float pg = g_pgen[n];
    float scale = pg / Sm;
    float c = 1.f - pg;

    for (int v = tid; v < VV; v += 256) row[v] = expf(row[v] - Mx) * scale;
    for (int q = 0; q < SS; q++) {
        int id = ids[b*SS + q];
        id = (id < 0) ? 0 : (id >= VV ? VV - 1 : id);
        if ((id & 255) == tid) row[id] += c * g_ahist[(size_t)n*SS + q];
    }

    float* orow = outp + ((size_t)n*T + t)*VV;
    float bv = -1e30f; int bi = VV - 1;
    for (int v = tid; v < VV; v += 256) {
        float x = row[v];
        orow[v] = x;
        if (x > bv) { bv = x; bi = v; }
    }
    sv[tid] = bv; si[tid] = bi; __syncthreads();
    #pragma unroll
    for (int off = BS/2; off > 0; off >>= 1) {
        if (tid < off) {
            if (sv[tid+off] > sv[tid] ||
                (sv[tid+off] == sv[tid] && si[tid+off] < si[tid])) {
                sv[tid] = sv[tid+off]; si[tid] = si[tid+off];
            }
        }
        __syncthreads();
    }
    if (tid == 0) {
        int fi = si[0];
        if (fi < 0) fi = 0; if (fi >= VV) fi = VV - 1;
        sWidx = fi;
    }
    __syncthreads();
    int widx = sWidx;
    float* wnext = wnxtOf(t);
    for (int h = tid; h < HH; h += 256)
        wnext[(size_t)n*HH + h] = embed[(size_t)widx*HH + h];
}

// ---- gate (t==0 only) ----
__global__ __launch_bounds__(256) void gate_kernel(
    const float* __restrict__ WgW, const float* __restrict__ Wgb,
    float* __restrict__ outg)
{
    int n = blockIdx.x;
    int tid = threadIdx.x;
    __shared__ float sc[BS];
    for (int g = 0; g < NGATE; g++) {
        float p = 0.f;
        for (int i = tid; i < HH; i += 256)
            p += g_ctx[(size_t)n*HH + i] * WgW[(size_t)g*HH + i];
        p = bsum(p, sc);
        if (tid == 0)
            outg[n*NGATE + g] = p + Wgb[g];
        __syncthreads();
    }
}

extern "C" void kernel_launch(void* const* d_in, const int* in_sizes, int n_in,
                              void* d_out, int out_size, void* d_ws, size_t ws_size,
                              hipStream_t stream)
{
    const int*   input_ids = (const int*)d_in[0];
    const float* enc       = (const float*)d_in[1];
    const float* hidden    = (const float*)d_in[2];
    const int*   masks     = (const int*)d_in[3];
    const int*   slot      = (const int*)d_in[4];
    // d_in[5] = max_len — T derived from out_size
    const float* embed     = (const float*)d_in[6];
    const float* Wih       = (const float*)d_in[7];
    const float* Whh       = (const float*)d_in[8];
    const float* bih       = (const float*)d_in[9];
    const float* bhh       = (const float*)d_in[10];
    const float* wgenW     = (const float*)d_in[11];
    const float* wgenb     = (const float*)d_in[12];
    const float* wgateW    = (const float*)d_in[13];
    const float* wgateb    = (const float*)d_in[14];
    float* out = (float*)d_out;     // f32 output (fingerprint-proven R6)
    const int lslot = in_sizes[4] / JJ;
    int T = (int)(((long long)out_size - (long long)NN*NGATE) / ((long long)NN*VV));
    if (T < 1) T = 1; if (T > 16) T = 16;
    (void)d_ws; (void)ws_size; (void)n_in;

    init_wh<<<NN, 256, 0, stream>>>(slot, embed, hidden, lslot);

    for (int t = 0; t < T; t++) {
        int wSel = (t & 1) ? 1 : 0;   // wcur
        int hSel = (t & 1) ? 3 : 2;   // hcur
        int nSel = (t & 1) ? 2 : 3;   // hnew

        gemm_abt<<<dim3(H3/64, 3), 256, 0, stream>>>(wSel, Wih, bih, 4, NN, HH, H3, H3);
        gemm_abt<<<dim3(H3/64, 3), 256, 0, stream>>>(hSel, Whh, bhh, 5, NN, HH, H3, H3);
        gru_combine<<<(NN*HH + 255)/256, 256, 0, stream>>>(t);

        score_gemm<<<dim3(SS/64, 1, BB), 256, 0, stream>>>(t, enc);
        attn_soft<<<NN, 256, 0, stream>>>(masks);
        ctx_gemm<<<dim3(HH/64, 1, BB), 256, 0, stream>>>(enc);
        pgen_kernel<<<NN, 256, 0, stream>>>(t, wgenW, wgenb);

        gemm_abt<<<dim3((VV + 63)/64, 3), 256, 0, stream>>>(nSel, embed, nullptr, 6,
                                                            NN, HH, VV, VV);
        vocab_out_kernel<<<NN, 256, 0, stream>>>(input_ids, embed, out, t, T);
        if (t == 0)
            gate_kernel<<<NN, 256, 0, stream>>>(wgateW, wgateb,
                                                out + (size_t)NN*T*VV);
    }
}